// Round 10
// baseline (76.429 us; speedup 1.0000x reference)
//
#include <hip/hip_runtime.h>
#include <math.h>

// CapsuleLinear routing — round 10: ZERO-LDS, ZERO-BARRIER, one wave per (b,o).
// Theory: R6-R9 (~24 us invariant) are bound on the per-CU DS pipe (LDS ops +
// shuffles); all reductions here are DPP (VALU pipe) + readlane->SGPR.
// Grid 4096 = (b,o), block = 64 threads. Lane L owns rows n = L + 64k, k<18,
// in fp32 VGPRs (144 regs). All math fp32 (better absmax than bf16-MFMA path).

#define NCAPS 1152
#define ILEN  8
#define OCAPS 64
#define OLEN  16
#define RPT   18      // rows per lane: 1152 / 64
#define NITER 3

template<int CTRL>
__device__ __forceinline__ float dpp_add(float x) {
    int xi = __builtin_bit_cast(int, x);
    int r  = __builtin_amdgcn_update_dpp(0, xi, CTRL, 0xf, 0xf, true);
    return x + __builtin_bit_cast(float, r);
}
// Full wave64 sum; valid in lane 63 (row_shr — verified R5/R7/R8).
__device__ __forceinline__ float wave_sum63(float v) {
    v = dpp_add<0x111>(v);
    v = dpp_add<0x112>(v);
    v = dpp_add<0x114>(v);
    v = dpp_add<0x118>(v);
    v = dpp_add<0x142>(v);   // row_bcast:15
    v = dpp_add<0x143>(v);   // row_bcast:31
    return v;
}
// Sum over each 16-lane row; valid in lane 15 of each row (verified R5).
__device__ __forceinline__ float row16_sum(float v) {
    v = dpp_add<0x111>(v);
    v = dpp_add<0x112>(v);
    v = dpp_add<0x114>(v);
    v = dpp_add<0x118>(v);
    return v;
}
__device__ __forceinline__ float bcast_lane(float v, int lane) {
    return __builtin_bit_cast(float,
        __builtin_amdgcn_readlane(__builtin_bit_cast(int, v), lane));
}

__global__ __launch_bounds__(64, 2) void caps_kernel(const float* __restrict__ x,
                                                     const float* __restrict__ w,
                                                     float* __restrict__ dout,
                                                     int probs_base) {
    const int lane = threadIdx.x;
    const int l16  = lane & 15;
    const int o = blockIdx.x & (OCAPS - 1);
    const int b = blockIdx.x >> 6;

    // W row for this lane's l16 (replicated across the 4 row-groups)
    const float4* wp = (const float4*)(w + ((size_t)o * OLEN + l16) * ILEN);
    const float4 wa = wp[0], wb = wp[1];
    float wd[ILEN];
    wd[0] = wa.x; wd[1] = wa.y; wd[2] = wa.z; wd[3] = wa.w;
    wd[4] = wb.x; wd[5] = wb.y; wd[6] = wb.z; wd[7] = wb.w;

    // x rows n = lane + 64k -> fp32 registers (coalesced float4 pairs)
    const float* xb = x + (size_t)b * NCAPS * ILEN;
    float xr[RPT][ILEN];
    #pragma unroll
    for (int k = 0; k < RPT; ++k) {
        const float4* q = (const float4*)(xb + (size_t)(lane + 64 * k) * ILEN);
        float4 a = q[0], c = q[1];
        xr[k][0] = a.x; xr[k][1] = a.y; xr[k][2] = a.z; xr[k][3] = a.w;
        xr[k][4] = c.x; xr[k][5] = c.y; xr[k][6] = c.z; xr[k][7] = c.w;
    }

    float ysg[ILEN];   // uniform after readlane (scalar operands)
    float e[RPT];
    float zinv = 0.f;

    #pragma unroll
    for (int it = 0; it <= NITER; ++it) {
        float s[ILEN];
        float z;
        if (it == 0) {
            #pragma unroll
            for (int i = 0; i < ILEN; ++i) {
                float acc = xr[0][i];
                #pragma unroll
                for (int k = 1; k < RPT; ++k) acc += xr[k][i];
                s[i] = acc;
            }
            z = (float)NCAPS;
        } else {
            #pragma unroll
            for (int k = 0; k < RPT; ++k) {
                float lg = xr[k][0] * ysg[0];
                #pragma unroll
                for (int i = 1; i < ILEN; ++i) lg = fmaf(xr[k][i], ysg[i], lg);
                e[k] = __expf(lg);   // |lg| <~ 11: no max-subtraction needed
            }
            #pragma unroll
            for (int i = 0; i < ILEN; ++i) {
                float acc = e[0] * xr[0][i];
                #pragma unroll
                for (int k = 1; k < RPT; ++k) acc = fmaf(e[k], xr[k][i], acc);
                s[i] = acc;
            }
            float zp = e[0];
            #pragma unroll
            for (int k = 1; k < RPT; ++k) zp += e[k];
            z = bcast_lane(wave_sum63(zp), 63);
        }

        // wave-reduce s -> uniform scalars (DPP + readlane, no DS pipe)
        float sg[ILEN];
        #pragma unroll
        for (int i = 0; i < ILEN; ++i) sg[i] = bcast_lane(wave_sum63(s[i]), 63);

        const float zi = 1.0f / z;
        // out_l for this lane's l16 (redundant across row-groups)
        float ol = wd[0] * sg[0];
        #pragma unroll
        for (int i = 1; i < ILEN; ++i) ol = fmaf(wd[i], sg[i], ol);
        ol *= zi;

        if (it < NITER) {
            float n2 = bcast_lane(row16_sum(ol * ol), 15);
            const float inv = 1.0f / fmaxf(sqrtf(n2), 1e-12f);
            const float oh = ol * inv;
            #pragma unroll
            for (int i = 0; i < ILEN; ++i)
                ysg[i] = bcast_lane(row16_sum(wd[i] * oh), 15);
        } else {
            zinv = zi;
            if (lane < OLEN) dout[((size_t)blockIdx.x << 4) + lane] = ol;
        }
    }

    // probs: lane L stores rows L + 64k -> consecutive lanes, consecutive dwords
    float* pp = dout + (size_t)probs_base + (size_t)blockIdx.x * NCAPS + lane;
    #pragma unroll
    for (int k = 0; k < RPT; ++k) pp[64 * k] = e[k] * zinv;
}

extern "C" void kernel_launch(void* const* d_in, const int* in_sizes, int n_in,
                              void* d_out, int out_size, void* d_ws, size_t ws_size,
                              hipStream_t stream) {
    const float* x = (const float*)d_in[0];
    const float* w = (const float*)d_in[1];
    float* out = (float*)d_out;
    const int Bv = in_sizes[0] / (NCAPS * ILEN);   // 64
    const int nblocks = Bv * OCAPS;                // 4096
    const int probs_base = nblocks * OLEN;         // 65536
    caps_kernel<<<dim3(nblocks), dim3(64), 0, stream>>>(x, w, out, probs_base);
}